// Round 7
// baseline (5161.290 us; speedup 1.0000x reference)
//
#include <hip/hip_runtime.h>
#include <hip/hip_fp16.h>

typedef _Float16 f16x8 __attribute__((ext_vector_type(8)));
typedef float f32x4 __attribute__((ext_vector_type(4)));

#define TT 512
#define HH 512
#define BB 64

// ws layout (bytes)
#define WS_LENS  4096         // int[64]
#define WS_HBUF  8192         // u32 tagged-h [dir][parity][64][512] = 524288 B (memset 0 each launch)
#define WS_END   (8192 + 524288)

// dynamic LDS layout (bytes)
#define LDS_W     0            // f16x8 [4 waves][32 k-slices][64 lanes] = 131072 B
#define LDS_GLDS  131072       // float [16][68] = 4352 B
#define LDS_H     135424       // f16 h-tile [16 rows][512 cols], XOR-swizzled = 16384 B
#define LDS_TOTAL 151808

#define MFMA(a, b, c) __builtin_amdgcn_mfma_f32_16x16x32_f16((a), (b), (c), 0, 0, 0)

__device__ __forceinline__ float fsig(float x) {
  float ax = __builtin_fabsf(x);
  float t  = __builtin_amdgcn_exp2f(-1.442695041f * ax);   // e^{-|x|}
  float r  = __builtin_amdgcn_rcpf(1.0f + t);
  return x >= 0.0f ? r : t * r;                            // sigmoid(x)
}
__device__ __forceinline__ float ftanh_(float x) {
  float ax = __builtin_fabsf(x);
  float t  = __builtin_amdgcn_exp2f(-2.885390082f * ax);   // e^{-2|x|}
  float r  = (1.0f - t) * __builtin_amdgcn_rcpf(1.0f + t); // tanh(|x|)
  return x >= 0.0f ? r : -r;
}

__global__ void len_kernel(const float* __restrict__ mask, int* __restrict__ lens) {
  int b = threadIdx.x;
  if (b < BB) {
    float s = 0.f;
    for (int t = 0; t < TT; ++t) s += mask[b * TT + t];
    lens[b] = (int)(s + 0.5f);
  }
}

// 256 blocks: bid = dir*128 + bg*32 + cg
//   dir in {0,1}; bg in [0,4): batches [bg*16, bg*16+16); cg in [0,32): h-cols [cg*16, cg*16+16)
// Each block computes gates[16 batches x 64 gate-cols] per step.
// h exchange: TAG-IN-DATA. hbuf words are u32 = (tag<<16)|f16bits, tag(h(s)) = s+2.
//   Producers: 1 relaxed agent dword store/thread (no drain, no flag).
//   Consumers: spin on the 32 words they need; x-part MFMAs run while h loads are in flight.
// Co-residency: 148 KB LDS -> exactly 1 block/CU; grid 256 = CU count.
__global__ void __launch_bounds__(256, 1)
bilstm_kernel(const float* __restrict__ x, const int* __restrict__ lens,
              const float* __restrict__ h0, const float* __restrict__ c0,
              const float* __restrict__ Wi_f, const float* __restrict__ Wh_f,
              const float* __restrict__ b_f,
              const float* __restrict__ Wi_b, const float* __restrict__ Wh_b,
              const float* __restrict__ b_b,
              float* __restrict__ out, unsigned int* hbuf)
{
  extern __shared__ __align__(16) char smem[];
  f16x8* wlds = (f16x8*)(smem + LDS_W);                 // [wv*32 + kk][ln]
  float (*glds)[68] = (float (*)[68])(smem + LDS_GLDS); // gates bounce [b_local][gate*16+i]
  char* htile = smem + LDS_H;                           // swizzled [16][1024B]

  const int bid = blockIdx.x;
  const int dir = bid >> 7;
  const int bg  = (bid >> 5) & 3;
  const int cg  = bid & 31;
  const int tid = threadIdx.x;
  const int wv  = tid >> 6;
  const int ln  = tid & 63;
  const int il  = ln & 15;   // MFMA M/N index
  const int kg  = ln >> 4;   // k-group 0..3

  const float* Wi = dir ? Wi_b : Wi_f;
  const float* Wh = dir ? Wh_b : Wh_f;
  const float* bv = dir ? b_b  : b_f;

  unsigned int* hb32 = hbuf + (size_t)dir * (2 * BB * HH);  // [parity][64][512] u32

  // ---- stationary weights -> LDS, f16 (each lane fills its own B-frag slots) ----
  const int jrow = wv * HH + cg * 16 + il;            // global gate row
#pragma unroll 4
  for (int kk = 0; kk < 32; ++kk) {
    int k0 = kk * 32 + kg * 8;
    const float* src = (k0 < 512) ? (Wi + (size_t)jrow * 512 + k0)
                                  : (Wh + (size_t)jrow * 512 + (k0 - 512));
    float4 f0 = *(const float4*)(src);
    float4 f1 = *(const float4*)(src + 4);
    f16x8 w;
    w[0] = (_Float16)f0.x; w[1] = (_Float16)f0.y; w[2] = (_Float16)f0.z; w[3] = (_Float16)f0.w;
    w[4] = (_Float16)f1.x; w[5] = (_Float16)f1.y; w[6] = (_Float16)f1.z; w[7] = (_Float16)f1.w;
    wlds[(wv * 32 + kk) * 64 + ln] = w;
  }
  const f16x8* wbase = wlds + (size_t)wv * 32 * 64 + ln;  // wbase[kk*64] = this lane's B-frag kk

  // ---- elementwise role: thread tid <-> (b_local = tid>>4, i = tid&15) ----
  const int bl_e  = tid >> 4;
  const int i_e   = tid & 15;
  const int b_e   = bg * 16 + bl_e;
  const int col_e = cg * 16 + i_e;
  float cst = c0[(size_t)b_e * HH + col_e];
  const float bi_ = bv[0 * HH + col_e];
  const float bf_ = bv[1 * HH + col_e];
  const float bg_ = bv[2 * HH + col_e];
  const float bo_ = bv[3 * HH + col_e];
  const int len_e = lens[b_e];

  // ---- gemm role: A-frag row = batch ----
  const int b_g   = bg * 16 + il;
  const int len_b = lens[b_g];

  // ---- init h(-1): parity 1, tag 1 ----
  {
    unsigned short hbits = __half_as_ushort(__float2half(h0[(size_t)b_e * HH + col_e]));
    unsigned int w0 = (1u << 16) | (unsigned int)hbits;
    __hip_atomic_store(hb32 + (size_t)1 * BB * HH + (size_t)b_e * HH + col_e, w0,
                       __ATOMIC_RELAXED, __HIP_MEMORY_SCOPE_AGENT);
  }
  __syncthreads();  // weight LDS fill visible before first x-MFMA

  for (int t = 0; t < TT; ++t) {
    // ---- issue h(t-1) tagged loads FIRST (latency hides under the x phase) ----
    const unsigned int* hs = hb32 + (size_t)((t + 1) & 1) * BB * HH + (size_t)bg * 16 * HH;
    const unsigned int expT = (unsigned int)(t + 1);   // tag of h(t-1)
    unsigned int hwv[8][4];
#pragma unroll
    for (int j = 0; j < 8; ++j) {
      const unsigned int* p = hs + j * 1024 + tid * 4;
      hwv[j][0] = __hip_atomic_load(p + 0, __ATOMIC_RELAXED, __HIP_MEMORY_SCOPE_AGENT);
      hwv[j][1] = __hip_atomic_load(p + 1, __ATOMIC_RELAXED, __HIP_MEMORY_SCOPE_AGENT);
      hwv[j][2] = __hip_atomic_load(p + 2, __ATOMIC_RELAXED, __HIP_MEMORY_SCOPE_AGENT);
      hwv[j][3] = __hip_atomic_load(p + 3, __ATOMIC_RELAXED, __HIP_MEMORY_SCOPE_AGENT);
    }

    // ---- x phase (independent of h): load f32, cvt f16, 16 x-MFMAs into acc ----
    int tsrc;
    if (dir == 0) tsrc = t;
    else { int v = len_b + (TT - 1) - t; if (v >= TT) v -= TT; tsrc = v; }
    const float* xrow = x + ((size_t)b_g * TT + tsrc) * 512;
    f16x8 ax[16];
#pragma unroll
    for (int kk = 0; kk < 16; ++kk) {
      float4 f0 = *(const float4*)(xrow + kk * 32 + kg * 8);
      float4 f1 = *(const float4*)(xrow + kk * 32 + kg * 8 + 4);
      f16x8 w;
      w[0] = (_Float16)f0.x; w[1] = (_Float16)f0.y; w[2] = (_Float16)f0.z; w[3] = (_Float16)f0.w;
      w[4] = (_Float16)f1.x; w[5] = (_Float16)f1.y; w[6] = (_Float16)f1.z; w[7] = (_Float16)f1.w;
      ax[kk] = w;
    }

    f32x4 ac0 = {0.f,0.f,0.f,0.f}, ac1 = {0.f,0.f,0.f,0.f};
    f32x4 ac2 = {0.f,0.f,0.f,0.f}, ac3 = {0.f,0.f,0.f,0.f};
#pragma unroll
    for (int kk = 0; kk < 16; kk += 4) {
      ac0 = MFMA(ax[kk + 0], wbase[(kk + 0) * 64], ac0);
      ac1 = MFMA(ax[kk + 1], wbase[(kk + 1) * 64], ac1);
      ac2 = MFMA(ax[kk + 2], wbase[(kk + 2) * 64], ac2);
      ac3 = MFMA(ax[kk + 3], wbase[(kk + 3) * 64], ac3);
    }

    // ---- tag check + spin (h usually arrived during the x phase) ----
    unsigned int pend = 0;
#pragma unroll
    for (int j = 0; j < 8; ++j) {
      bool ok = ((hwv[j][0] >> 16) == expT) && ((hwv[j][1] >> 16) == expT) &&
                ((hwv[j][2] >> 16) == expT) && ((hwv[j][3] >> 16) == expT);
      if (!ok) pend |= (1u << j);
    }
    while (pend) {
      __builtin_amdgcn_s_sleep(2);
#pragma unroll
      for (int j = 0; j < 8; ++j) {
        if (pend & (1u << j)) {
          const unsigned int* p = hs + j * 1024 + tid * 4;
          unsigned int a0 = __hip_atomic_load(p + 0, __ATOMIC_RELAXED, __HIP_MEMORY_SCOPE_AGENT);
          unsigned int a1 = __hip_atomic_load(p + 1, __ATOMIC_RELAXED, __HIP_MEMORY_SCOPE_AGENT);
          unsigned int a2 = __hip_atomic_load(p + 2, __ATOMIC_RELAXED, __HIP_MEMORY_SCOPE_AGENT);
          unsigned int a3 = __hip_atomic_load(p + 3, __ATOMIC_RELAXED, __HIP_MEMORY_SCOPE_AGENT);
          if (((a0 >> 16) == expT) && ((a1 >> 16) == expT) &&
              ((a2 >> 16) == expT) && ((a3 >> 16) == expT)) {
            hwv[j][0] = a0; hwv[j][1] = a1; hwv[j][2] = a2; hwv[j][3] = a3;
            pend &= ~(1u << j);
          }
        }
      }
    }

    // ---- stage h into swizzled LDS tile (strip tags, pack 4 f16 -> 8B) ----
#pragma unroll
    for (int j = 0; j < 8; ++j) {
      int row = j * 2 + (tid >> 7);
      unsigned int lo = (hwv[j][0] & 0xFFFFu) | (hwv[j][1] << 16);
      unsigned int hi = (hwv[j][2] & 0xFFFFu) | (hwv[j][3] << 16);
      int byo = (((tid & 127) * 8) ^ ((row & 7) << 4));
      uint2 v; v.x = lo; v.y = hi;
      *(uint2*)(htile + row * 1024 + byo) = v;
    }
    __syncthreads();   // B2: htile ready (everyone finished prev-step fh reads before B3)

    // ---- h A-frags: one ds_read_b128 per K-slice (swizzle matches the write) ----
    f16x8 fh[16];
#pragma unroll
    for (int kk = 0; kk < 16; ++kk) {
      int inr = kk * 64 + kg * 16;
      fh[kk] = *(const f16x8*)(htile + il * 1024 + (inr ^ ((il & 7) << 4)));
    }

    // ---- 16 h-MFMAs accumulate on top of the x part ----
#pragma unroll
    for (int kk = 0; kk < 16; kk += 4) {
      ac0 = MFMA(fh[kk + 0], wbase[(16 + kk + 0) * 64], ac0);
      ac1 = MFMA(fh[kk + 1], wbase[(16 + kk + 1) * 64], ac1);
      ac2 = MFMA(fh[kk + 2], wbase[(16 + kk + 2) * 64], ac2);
      ac3 = MFMA(fh[kk + 3], wbase[(16 + kk + 3) * 64], ac3);
    }

    // D-frag: col = lane&15, row = (lane>>4)*4 + r  (m89-verified, dtype-independent)
#pragma unroll
    for (int r = 0; r < 4; ++r)
      glds[kg * 4 + r][wv * 16 + il] = ac0[r] + ac1[r] + ac2[r] + ac3[r];
    __syncthreads();   // B3: glds ready

    // ---- LSTM cell (gate order i,f,g,o) ----
    float gi = glds[bl_e][ 0 + i_e] + bi_;
    float gf = glds[bl_e][16 + i_e] + bf_;
    float gg = glds[bl_e][32 + i_e] + bg_;
    float go = glds[bl_e][48 + i_e] + bo_;
    float si = fsig(gi), sf = fsig(gf), so = fsig(go);
    float tg = ftanh_(gg);
    cst = sf * cst + si * tg;
    float hv = so * ftanh_(cst);

    // ---- publish h(t): single tagged dword store (tag t+2), parity t&1 ----
    {
      unsigned short hbits = __half_as_ushort(__float2half(hv));
      unsigned int pw = ((unsigned int)(t + 2) << 16) | (unsigned int)hbits;
      __hip_atomic_store(hb32 + (size_t)(t & 1) * BB * HH + (size_t)b_e * HH + col_e, pw,
                         __ATOMIC_RELAXED, __HIP_MEMORY_SCOPE_AGENT);
    }

    // ---- HBM out store AFTER publish: off the inter-block critical path ----
    if (dir == 0) {
      out[((size_t)b_e * TT + t) * (2 * HH) + col_e] = hv;
    } else {
      int td = len_e - 1 - t; if (td < 0) td += TT;
      out[((size_t)b_e * TT + td) * (2 * HH) + HH + col_e] = hv;
    }
  }
}

extern "C" void kernel_launch(void* const* d_in, const int* in_sizes, int n_in,
                              void* d_out, int out_size, void* d_ws, size_t ws_size,
                              hipStream_t stream) {
  const float* x    = (const float*)d_in[0];
  const float* mask = (const float*)d_in[1];
  const float* h0   = (const float*)d_in[2];
  const float* c0   = (const float*)d_in[3];
  const float* Wi_f = (const float*)d_in[4];
  const float* Wh_f = (const float*)d_in[5];
  const float* b_f  = (const float*)d_in[6];
  const float* Wi_b = (const float*)d_in[7];
  const float* Wh_b = (const float*)d_in[8];
  const float* b_b  = (const float*)d_in[9];
  float* out = (float*)d_out;

  char* ws = (char*)d_ws;
  int*          lens = (int*)(ws + WS_LENS);
  unsigned int* hbuf = (unsigned int*)(ws + WS_HBUF);

  // zero the tagged-h region every call (tags restart at 1; memset-0 never matches)
  hipMemsetAsync(ws, 0, WS_END, stream);

  hipLaunchKernelGGL(len_kernel, dim3(1), dim3(64), 0, stream, mask, lens);

  // opt-in to >64KB dynamic LDS (idempotent, not a stream op -> graph-capture safe)
  hipFuncSetAttribute((const void*)bilstm_kernel,
                      hipFuncAttributeMaxDynamicSharedMemorySize, LDS_TOTAL);

  // Plain (non-cooperative) launch: 148KB LDS -> 1 block/CU, grid == CU count,
  // so all 256 blocks are co-resident at dispatch; sync is tag-in-data.
  hipLaunchKernelGGL(bilstm_kernel, dim3(256), dim3(256), LDS_TOTAL, stream,
                     x, lens, h0, c0, Wi_f, Wh_f, b_f, Wi_b, Wh_b, b_b,
                     out, hbuf);
}

// Round 8
// 3325.994 us; speedup vs baseline: 1.5518x; 1.5518x over previous
//
#include <hip/hip_runtime.h>
#include <hip/hip_fp16.h>

typedef _Float16 f16x8 __attribute__((ext_vector_type(8)));
typedef float f32x4 __attribute__((ext_vector_type(4)));

#define TT 512
#define HH 512
#define BB 64

// ws layout (bytes)
#define WS_LENS  4096         // int[64]
#define WS_HBUF  8192         // u64 tagged-h [dir][parity][64][256] = 524288 B (memset 0 each launch)
#define WS_END   (8192 + 524288)

// dynamic LDS layout (bytes)
#define LDS_W     0            // f16x8 [4 waves][32 k-slices][64 lanes] = 131072 B
#define LDS_GLDS  131072       // float [16][68] = 4352 B
#define LDS_H     135424       // f16 h-tile [16 rows][512 cols], XOR-swizzled = 16384 B
#define LDS_TOTAL 151808

#define MFMA(a, b, c) __builtin_amdgcn_mfma_f32_16x16x32_f16((a), (b), (c), 0, 0, 0)

__device__ __forceinline__ float fsig(float x) {
  float ax = __builtin_fabsf(x);
  float t  = __builtin_amdgcn_exp2f(-1.442695041f * ax);   // e^{-|x|}
  float r  = __builtin_amdgcn_rcpf(1.0f + t);
  return x >= 0.0f ? r : t * r;                            // sigmoid(x)
}
__device__ __forceinline__ float ftanh_(float x) {
  float ax = __builtin_fabsf(x);
  float t  = __builtin_amdgcn_exp2f(-2.885390082f * ax);   // e^{-2|x|}
  float r  = (1.0f - t) * __builtin_amdgcn_rcpf(1.0f + t); // tanh(|x|)
  return x >= 0.0f ? r : -r;
}

__global__ void len_kernel(const float* __restrict__ mask, int* __restrict__ lens) {
  int b = threadIdx.x;
  if (b < BB) {
    float s = 0.f;
    for (int t = 0; t < TT; ++t) s += mask[b * TT + t];
    lens[b] = (int)(s + 0.5f);
  }
}

// 256 blocks: bid = dir*128 + bg*32 + cg
//   dir in {0,1}; bg in [0,4): batches [bg*16, bg*16+16); cg in [0,32): h-cols [cg*16, cg*16+16)
// h exchange: TAG-IN-DATA, u64 units {tag:32, h_odd:f16, h_even:f16}.
//   Producer: even threads issue ONE relaxed u64 agent store (no drain, no flag).
//   Consumer: 16 dense u64 loads/thread issued BEFORE the x phase; tag check after
//   (vmcnt is issue-ordered, so x-operand consumption implies h loads returned).
// Overwrite safety: peer's tag-(t+1) publish is data-dependent on its tag-t reads,
//   so observing t+1 everywhere proves tag-t reads are complete -> safe to overwrite.
// Co-residency: 148 KB LDS -> exactly 1 block/CU; grid 256 = CU count.
__global__ void __launch_bounds__(256, 1)
bilstm_kernel(const float* __restrict__ x, const int* __restrict__ lens,
              const float* __restrict__ h0, const float* __restrict__ c0,
              const float* __restrict__ Wi_f, const float* __restrict__ Wh_f,
              const float* __restrict__ b_f,
              const float* __restrict__ Wi_b, const float* __restrict__ Wh_b,
              const float* __restrict__ b_b,
              float* __restrict__ out, unsigned long long* hbuf)
{
  extern __shared__ __align__(16) char smem[];
  f16x8* wlds = (f16x8*)(smem + LDS_W);                 // [wv*32 + kk][ln]
  float (*glds)[68] = (float (*)[68])(smem + LDS_GLDS); // gates bounce [b_local][gate*16+i]
  char* htile = smem + LDS_H;                           // swizzled [16][1024B]

  const int bid = blockIdx.x;
  const int dir = bid >> 7;
  const int bg  = (bid >> 5) & 3;
  const int cg  = bid & 31;
  const int tid = threadIdx.x;
  const int wv  = tid >> 6;
  const int ln  = tid & 63;
  const int il  = ln & 15;   // MFMA M/N index
  const int kg  = ln >> 4;   // k-group 0..3

  const float* Wi = dir ? Wi_b : Wi_f;
  const float* Wh = dir ? Wh_b : Wh_f;
  const float* bv = dir ? b_b  : b_f;

  unsigned long long* hb64 = hbuf + (size_t)dir * (2 * BB * 256);  // [parity][64][256] u64

  // ---- stationary weights -> LDS, f16 (each lane fills its own B-frag slots) ----
  const int jrow = wv * HH + cg * 16 + il;            // global gate row
#pragma unroll 4
  for (int kk = 0; kk < 32; ++kk) {
    int k0 = kk * 32 + kg * 8;
    const float* src = (k0 < 512) ? (Wi + (size_t)jrow * 512 + k0)
                                  : (Wh + (size_t)jrow * 512 + (k0 - 512));
    float4 f0 = *(const float4*)(src);
    float4 f1 = *(const float4*)(src + 4);
    f16x8 w;
    w[0] = (_Float16)f0.x; w[1] = (_Float16)f0.y; w[2] = (_Float16)f0.z; w[3] = (_Float16)f0.w;
    w[4] = (_Float16)f1.x; w[5] = (_Float16)f1.y; w[6] = (_Float16)f1.z; w[7] = (_Float16)f1.w;
    wlds[(wv * 32 + kk) * 64 + ln] = w;
  }
  const f16x8* wbase = wlds + (size_t)wv * 32 * 64 + ln;  // wbase[kk*64] = this lane's B-frag kk

  // ---- elementwise role: thread tid <-> (b_local = tid>>4, i = tid&15) ----
  const int bl_e  = tid >> 4;
  const int i_e   = tid & 15;
  const int b_e   = bg * 16 + bl_e;
  const int col_e = cg * 16 + i_e;
  float cst = c0[(size_t)b_e * HH + col_e];
  const float bi_ = bv[0 * HH + col_e];
  const float bf_ = bv[1 * HH + col_e];
  const float bg_ = bv[2 * HH + col_e];
  const float bo_ = bv[3 * HH + col_e];
  const int len_e = lens[b_e];

  // ---- gemm role: A-frag row = batch ----
  const int b_g   = bg * 16 + il;
  const int len_b = lens[b_g];

  // ---- init h(-1): parity 1, tag 1, paired u64 ----
  {
    unsigned int hbits = __half_as_ushort(__float2half(h0[(size_t)b_e * HH + col_e]));
    unsigned int pb = __shfl_xor((int)hbits, 1);
    if ((tid & 1) == 0) {
      unsigned long long pw = (1ull << 32) | ((unsigned long long)pb << 16) | hbits;
      __hip_atomic_store(hb64 + (size_t)1 * BB * 256 + (size_t)b_e * 256 + (col_e >> 1), pw,
                         __ATOMIC_RELAXED, __HIP_MEMORY_SCOPE_AGENT);
    }
  }
  __syncthreads();  // weight LDS fill visible before first x-MFMA

  for (int t = 0; t < TT; ++t) {
    // ---- issue h(t-1) tagged u64 loads FIRST (dense: lane i -> unit i) ----
    const unsigned long long* hs = hb64 + (size_t)((t + 1) & 1) * BB * 256 + (size_t)bg * 16 * 256;
    const unsigned int expT = (unsigned int)(t + 1);   // tag of h(t-1)
    unsigned long long hwv[16];
#pragma unroll
    for (int s = 0; s < 16; ++s)
      hwv[s] = __hip_atomic_load(hs + s * 256 + tid, __ATOMIC_RELAXED, __HIP_MEMORY_SCOPE_AGENT);

    // ---- x phase (independent of h): load f32, cvt f16 ----
    int tsrc;
    if (dir == 0) tsrc = t;
    else { int v = len_b + (TT - 1) - t; if (v >= TT) v -= TT; tsrc = v; }
    const float* xrow = x + ((size_t)b_g * TT + tsrc) * 512;
    f16x8 ax[16];
#pragma unroll
    for (int kk = 0; kk < 16; ++kk) {
      float4 f0 = *(const float4*)(xrow + kk * 32 + kg * 8);
      float4 f1 = *(const float4*)(xrow + kk * 32 + kg * 8 + 4);
      f16x8 w;
      w[0] = (_Float16)f0.x; w[1] = (_Float16)f0.y; w[2] = (_Float16)f0.z; w[3] = (_Float16)f0.w;
      w[4] = (_Float16)f1.x; w[5] = (_Float16)f1.y; w[6] = (_Float16)f1.z; w[7] = (_Float16)f1.w;
      ax[kk] = w;
    }

    // ---- 16 x-MFMAs (covers h-load latency; vmcnt in-order => h loads done after) ----
    f32x4 ac0 = {0.f,0.f,0.f,0.f}, ac1 = {0.f,0.f,0.f,0.f};
    f32x4 ac2 = {0.f,0.f,0.f,0.f}, ac3 = {0.f,0.f,0.f,0.f};
#pragma unroll
    for (int kk = 0; kk < 16; kk += 4) {
      ac0 = MFMA(ax[kk + 0], wbase[(kk + 0) * 64], ac0);
      ac1 = MFMA(ax[kk + 1], wbase[(kk + 1) * 64], ac1);
      ac2 = MFMA(ax[kk + 2], wbase[(kk + 2) * 64], ac2);
      ac3 = MFMA(ax[kk + 3], wbase[(kk + 3) * 64], ac3);
    }

    // ---- tag check; slow path: dense reload-all + sleep ----
    {
      bool ok = true;
#pragma unroll
      for (int s = 0; s < 16; ++s) ok &= ((unsigned int)(hwv[s] >> 32) == expT);
      while (!__all(ok)) {
        __builtin_amdgcn_s_sleep(2);
#pragma unroll
        for (int s = 0; s < 16; ++s)
          hwv[s] = __hip_atomic_load(hs + s * 256 + tid, __ATOMIC_RELAXED, __HIP_MEMORY_SCOPE_AGENT);
        ok = true;
#pragma unroll
        for (int s = 0; s < 16; ++s) ok &= ((unsigned int)(hwv[s] >> 32) == expT);
      }
    }

    // ---- stage h into swizzled LDS tile (strip tags; 4B = 2 f16 per unit) ----
#pragma unroll
    for (int s = 0; s < 16; ++s) {
      unsigned int lo = (unsigned int)hwv[s];           // [h_odd:16 | h_even:16]
      *(unsigned int*)(htile + s * 1024 + ((tid * 4) ^ ((s & 7) << 4))) = lo;
    }
    __syncthreads();   // B2: htile ready (prev-step fh reads finished before B3)

    // ---- h A-frags: one ds_read_b128 per K-slice (swizzle matches the write) ----
    f16x8 fh[16];
#pragma unroll
    for (int kk = 0; kk < 16; ++kk) {
      int inr = kk * 64 + kg * 16;
      fh[kk] = *(const f16x8*)(htile + il * 1024 + (inr ^ ((il & 7) << 4)));
    }

    // ---- 16 h-MFMAs accumulate on top of the x part ----
#pragma unroll
    for (int kk = 0; kk < 16; kk += 4) {
      ac0 = MFMA(fh[kk + 0], wbase[(16 + kk + 0) * 64], ac0);
      ac1 = MFMA(fh[kk + 1], wbase[(16 + kk + 1) * 64], ac1);
      ac2 = MFMA(fh[kk + 2], wbase[(16 + kk + 2) * 64], ac2);
      ac3 = MFMA(fh[kk + 3], wbase[(16 + kk + 3) * 64], ac3);
    }

    // D-frag: col = lane&15, row = (lane>>4)*4 + r  (m89-verified, dtype-independent)
#pragma unroll
    for (int r = 0; r < 4; ++r)
      glds[kg * 4 + r][wv * 16 + il] = ac0[r] + ac1[r] + ac2[r] + ac3[r];
    __syncthreads();   // B3: glds ready

    // ---- LSTM cell (gate order i,f,g,o) ----
    float gi = glds[bl_e][ 0 + i_e] + bi_;
    float gf = glds[bl_e][16 + i_e] + bf_;
    float gg = glds[bl_e][32 + i_e] + bg_;
    float go = glds[bl_e][48 + i_e] + bo_;
    float si = fsig(gi), sf = fsig(gf), so = fsig(go);
    float tg = ftanh_(gg);
    cst = sf * cst + si * tg;
    float hv = so * ftanh_(cst);

    // ---- publish h(t): paired u64 tagged store (tag t+2), parity t&1 ----
    {
      unsigned int hbits = __half_as_ushort(__float2half(hv));
      unsigned int pb = __shfl_xor((int)hbits, 1);
      if ((tid & 1) == 0) {
        unsigned long long pw = ((unsigned long long)(unsigned int)(t + 2) << 32)
                              | ((unsigned long long)pb << 16) | hbits;
        __hip_atomic_store(hb64 + (size_t)(t & 1) * BB * 256 + (size_t)b_e * 256 + (col_e >> 1), pw,
                           __ATOMIC_RELAXED, __HIP_MEMORY_SCOPE_AGENT);
      }
    }

    // ---- HBM out store AFTER publish: off the inter-block critical path ----
    if (dir == 0) {
      out[((size_t)b_e * TT + t) * (2 * HH) + col_e] = hv;
    } else {
      int td = len_e - 1 - t; if (td < 0) td += TT;
      out[((size_t)b_e * TT + td) * (2 * HH) + HH + col_e] = hv;
    }
  }
}

extern "C" void kernel_launch(void* const* d_in, const int* in_sizes, int n_in,
                              void* d_out, int out_size, void* d_ws, size_t ws_size,
                              hipStream_t stream) {
  const float* x    = (const float*)d_in[0];
  const float* mask = (const float*)d_in[1];
  const float* h0   = (const float*)d_in[2];
  const float* c0   = (const float*)d_in[3];
  const float* Wi_f = (const float*)d_in[4];
  const float* Wh_f = (const float*)d_in[5];
  const float* b_f  = (const float*)d_in[6];
  const float* Wi_b = (const float*)d_in[7];
  const float* Wh_b = (const float*)d_in[8];
  const float* b_b  = (const float*)d_in[9];
  float* out = (float*)d_out;

  char* ws = (char*)d_ws;
  int*                lens = (int*)(ws + WS_LENS);
  unsigned long long* hbuf = (unsigned long long*)(ws + WS_HBUF);

  // zero the tagged-h region every call (tags restart at 1; memset-0 never matches)
  hipMemsetAsync(ws, 0, WS_END, stream);

  hipLaunchKernelGGL(len_kernel, dim3(1), dim3(64), 0, stream, mask, lens);

  // opt-in to >64KB dynamic LDS (idempotent, not a stream op -> graph-capture safe)
  hipFuncSetAttribute((const void*)bilstm_kernel,
                      hipFuncAttributeMaxDynamicSharedMemorySize, LDS_TOTAL);

  // Plain (non-cooperative) launch: 148KB LDS -> 1 block/CU, grid == CU count,
  // so all 256 blocks are co-resident at dispatch; sync is tag-in-data.
  hipLaunchKernelGGL(bilstm_kernel, dim3(256), dim3(256), LDS_TOTAL, stream,
                     x, lens, h0, c0, Wi_f, Wh_f, b_f, Wi_b, Wh_b, b_b,
                     out, hbuf);
}

// Round 9
// 3133.256 us; speedup vs baseline: 1.6473x; 1.0615x over previous
//
#include <hip/hip_runtime.h>
#include <hip/hip_fp16.h>

typedef _Float16 f16x8 __attribute__((ext_vector_type(8)));
typedef float f32x4 __attribute__((ext_vector_type(4)));
typedef unsigned int u32x4 __attribute__((ext_vector_type(4)));

#define TT 512
#define HH 512

// ws layout (bytes)
#define WS_CLAIM 0            // int[8] role counters (memset each call)
#define WS_LENS  4096         // int[64]
#define WS_HBUF  8192         // u32 tagged-h [8 grp][2 parity][16 b][512 col] = 512 KB (NOT memset; replay-safe by tag design)

// dynamic LDS (bytes)
#define LDS_HT    0           // frag-major h tile [kk=16][kg=4][il=16] x 16B = 16 KB
#define LDS_GLDS  16384       // float [16][68] gates bounce
#define LDS_TOTAL 90112       // padded >80KB to hard-force 1 block/CU

#define MFMA(a,b,c) __builtin_amdgcn_mfma_f32_16x16x32_f16((a),(b),(c),0,0,0)

__device__ __forceinline__ float fsig(float x) {
  float ax = __builtin_fabsf(x);
  float t  = __builtin_amdgcn_exp2f(-1.442695041f * ax);
  float r  = __builtin_amdgcn_rcpf(1.0f + t);
  return x >= 0.0f ? r : t * r;
}
__device__ __forceinline__ float ftanh_(float x) {
  float ax = __builtin_fabsf(x);
  float t  = __builtin_amdgcn_exp2f(-2.885390082f * ax);
  float r  = (1.0f - t) * __builtin_amdgcn_rcpf(1.0f + t);
  return x >= 0.0f ? r : -r;
}
__device__ __forceinline__ f16x8 cvt8(const float* p) {
  float4 a = *(const float4*)p, b = *(const float4*)(p + 4);
  f16x8 w;
  w[0]=(_Float16)a.x; w[1]=(_Float16)a.y; w[2]=(_Float16)a.z; w[3]=(_Float16)a.w;
  w[4]=(_Float16)b.x; w[5]=(_Float16)b.y; w[6]=(_Float16)b.z; w[7]=(_Float16)b.w;
  return w;
}

__global__ void len_kernel(const float* __restrict__ mask, int* __restrict__ lens) {
  int b = threadIdx.x;
  if (b < 64) {
    float s = 0.f;
    for (int t = 0; t < TT; ++t) s += mask[b * TT + t];
    lens[b] = (int)(s + 0.5f);
  }
}

// INTRA-XCD BiLSTM: group = XCD (via HW_REG_XCC_ID + atomic role claim).
//   grp = xcc (0..7) -> dir = grp>>2, bg = grp&3;  cg = claimed role (0..31).
// All h exchange stays inside one XCD's L2: publishes are sc0 stores (L1 is
// write-through on CDNA -> visible in local L2), consumes are sc0 loads (bypass
// stale L1, hit local L2). Tag-in-data u32 {tag16|h16}, tag(h(s)) = s+2.
// Replay-safe w/o memset: stale tags are 512/513, first-read expT is 1/2, and
// max inter-block skew is 1 step (block at t implies all peers >= t-1).
// Weights live in VGPRs, pinned by an empty-asm "+v" each iteration.
// Co-residency: 88KB LDS -> 1 block/CU; 256 blocks co-resident (proven r4-r8)
// -> exactly 32 blocks per XCD -> claim yields roles 0..31.
__global__ void __launch_bounds__(256, 1)
bilstm_kernel(const float* __restrict__ x, const int* __restrict__ lens,
              const float* __restrict__ h0, const float* __restrict__ c0,
              const float* __restrict__ Wi_f, const float* __restrict__ Wh_f,
              const float* __restrict__ b_f,
              const float* __restrict__ Wi_b, const float* __restrict__ Wh_b,
              const float* __restrict__ b_b,
              float* __restrict__ out, unsigned int* hbuf, int* claim)
{
  extern __shared__ __align__(16) char smem[];
  char* htile = smem + LDS_HT;
  float (*glds)[68] = (float (*)[68])(smem + LDS_GLDS);

  const int tid = threadIdx.x;

  __shared__ int role_sh;
  if (tid == 0) {
    unsigned int xcc;
    asm volatile("s_getreg_b32 %0, hwreg(HW_REG_XCC_ID)" : "=s"(xcc));
    int r = __hip_atomic_fetch_add(&claim[xcc & 7], 1, __ATOMIC_RELAXED,
                                   __HIP_MEMORY_SCOPE_AGENT);
    role_sh = (int)((xcc & 7) << 5) | (r & 31);
  }
  __syncthreads();
  const int grp = role_sh >> 5;   // = XCD id
  const int cg  = role_sh & 31;   // col-group role within XCD
  const int dir = grp >> 2;
  const int bg  = grp & 3;

  const int wv = tid >> 6, ln = tid & 63, il = ln & 15, kg = ln >> 4;

  const float* Wi = dir ? Wi_b : Wi_f;
  const float* Wh = dir ? Wh_b : Wh_f;
  const float* bv = dir ? b_b  : b_f;

  unsigned int* gbase = hbuf + (size_t)grp * 16384;   // [2][16][512] u32

  // ---- stationary weights -> REGISTERS (pinned in-loop via empty asm) ----
  const int jrow = wv * HH + cg * 16 + il;
  f16x8 wreg[32];
#pragma unroll
  for (int kk = 0; kk < 32; ++kk) {
    int k0 = kk * 32 + kg * 8;
    const float* src = (k0 < 512) ? (Wi + (size_t)jrow * 512 + k0)
                                  : (Wh + (size_t)jrow * 512 + (k0 - 512));
    wreg[kk] = cvt8(src);
  }

  // ---- elementwise role ----
  const int bl_e = tid >> 4, i_e = tid & 15;
  const int b_e = bg * 16 + bl_e, col_e = cg * 16 + i_e;
  float cst = c0[(size_t)b_e * HH + col_e];
  const float bi_ = bv[0*HH+col_e], bf_ = bv[1*HH+col_e],
              bg_ = bv[2*HH+col_e], bo_ = bv[3*HH+col_e];
  const int len_e = lens[b_e];

  // ---- gemm role: A-frag row = batch ----
  const int b_g = bg * 16 + il;
  const int len_b = lens[b_g];

  // ---- init h(-1): parity 1, tag 1 (sc0 -> local L2) ----
  {
    unsigned int hb = __half_as_ushort(__float2half(h0[(size_t)b_e * HH + col_e]));
    unsigned int pw = (1u << 16) | hb;
    unsigned int* hp = gbase + 8192 + bl_e * 512 + col_e;
    asm volatile("global_store_dword %0, %1, off sc0" :: "v"(hp), "v"(pw) : "memory");
  }

#define TCHK(a) ((a[0]^pat)|(a[1]^pat)|(a[2]^pat)|(a[3]^pat))
#define PK(lo,hi) (((lo)&0xffffu)|((hi)<<16))

  for (int t = 0; t < TT; ++t) {
    // pin the weight fragments in VGPRs (defeats remat; zero instructions)
    asm volatile("" : "+v"(wreg[0]),"+v"(wreg[1]),"+v"(wreg[2]),"+v"(wreg[3]),
                      "+v"(wreg[4]),"+v"(wreg[5]),"+v"(wreg[6]),"+v"(wreg[7]),
                      "+v"(wreg[8]),"+v"(wreg[9]),"+v"(wreg[10]),"+v"(wreg[11]),
                      "+v"(wreg[12]),"+v"(wreg[13]),"+v"(wreg[14]),"+v"(wreg[15]));
    asm volatile("" : "+v"(wreg[16]),"+v"(wreg[17]),"+v"(wreg[18]),"+v"(wreg[19]),
                      "+v"(wreg[20]),"+v"(wreg[21]),"+v"(wreg[22]),"+v"(wreg[23]),
                      "+v"(wreg[24]),"+v"(wreg[25]),"+v"(wreg[26]),"+v"(wreg[27]),
                      "+v"(wreg[28]),"+v"(wreg[29]),"+v"(wreg[30]),"+v"(wreg[31]));

    // ---- x phase (independent of h): load f32 -> cvt -> 16 x-MFMAs ----
    int tsrc;
    if (dir == 0) tsrc = t;
    else { int v = len_b + (TT - 1) - t; if (v >= TT) v -= TT; tsrc = v; }
    const float* xrow = x + ((size_t)b_g * TT + tsrc) * 512;

    f32x4 ac0 = {0.f,0.f,0.f,0.f}, ac1 = {0.f,0.f,0.f,0.f};
    f32x4 ac2 = {0.f,0.f,0.f,0.f}, ac3 = {0.f,0.f,0.f,0.f};
#pragma unroll
    for (int kq = 0; kq < 4; ++kq) {
      f16x8 w0 = cvt8(xrow + (kq*4+0)*32 + kg*8);
      f16x8 w1 = cvt8(xrow + (kq*4+1)*32 + kg*8);
      f16x8 w2 = cvt8(xrow + (kq*4+2)*32 + kg*8);
      f16x8 w3 = cvt8(xrow + (kq*4+3)*32 + kg*8);
      ac0 = MFMA(w0, wreg[kq*4+0], ac0);
      ac1 = MFMA(w1, wreg[kq*4+1], ac1);
      ac2 = MFMA(w2, wreg[kq*4+2], ac2);
      ac3 = MFMA(w3, wreg[kq*4+3], ac3);
    }
    __builtin_amdgcn_sched_barrier(0);

    // ---- h(t-1): dense 128B/thread sc0 loads from local L2, tag-validated ----
    const unsigned int* hp = gbase + ((t + 1) & 1) * 8192 + tid * 32;
    const unsigned int expT = (unsigned int)(t + 1);
    const unsigned int pat = expT << 16;
    u32x4 a0,a1,a2,a3,a4,a5,a6,a7;
    for (;;) {
      asm volatile(
        "global_load_dwordx4 %0, %8, off sc0\n\t"
        "global_load_dwordx4 %1, %8, off offset:16 sc0\n\t"
        "global_load_dwordx4 %2, %8, off offset:32 sc0\n\t"
        "global_load_dwordx4 %3, %8, off offset:48 sc0\n\t"
        "global_load_dwordx4 %4, %8, off offset:64 sc0\n\t"
        "global_load_dwordx4 %5, %8, off offset:80 sc0\n\t"
        "global_load_dwordx4 %6, %8, off offset:96 sc0\n\t"
        "global_load_dwordx4 %7, %8, off offset:112 sc0\n\t"
        "s_waitcnt vmcnt(0)"
        : "=&v"(a0),"=&v"(a1),"=&v"(a2),"=&v"(a3),
          "=&v"(a4),"=&v"(a5),"=&v"(a6),"=&v"(a7)
        : "v"(hp) : "memory");
      unsigned int m = TCHK(a0)|TCHK(a1)|TCHK(a2)|TCHK(a3)
                      |TCHK(a4)|TCHK(a5)|TCHK(a6)|TCHK(a7);
      if ((m >> 16) == 0) break;
      __builtin_amdgcn_s_sleep(1);
    }

    // ---- stage into frag-major LDS tile: htile[kk][kg][il], XOR on il slot ----
    // thread (r_=tid>>4 row, c_=tid&15 -> kk) holds cols c_*32..+32 of row r_
    u32x4 p0, p1, p2, p3;
    p0[0]=PK(a0[0],a0[1]); p0[1]=PK(a0[2],a0[3]); p0[2]=PK(a1[0],a1[1]); p0[3]=PK(a1[2],a1[3]);
    p1[0]=PK(a2[0],a2[1]); p1[1]=PK(a2[2],a2[3]); p1[2]=PK(a3[0],a3[1]); p1[3]=PK(a3[2],a3[3]);
    p2[0]=PK(a4[0],a4[1]); p2[1]=PK(a4[2],a4[3]); p2[2]=PK(a5[0],a5[1]); p2[3]=PK(a5[2],a5[3]);
    p3[0]=PK(a6[0],a6[1]); p3[1]=PK(a6[2],a6[3]); p3[2]=PK(a7[0],a7[1]); p3[3]=PK(a7[2],a7[3]);
    {
      const int r_ = tid >> 4, c_ = tid & 15;
      char* wbp = htile + c_ * 1024 + ((r_ * 16) ^ ((c_ & 7) << 4));
      *(u32x4*)(wbp +   0) = p0;   // kg=0
      *(u32x4*)(wbp + 256) = p1;   // kg=1
      *(u32x4*)(wbp + 512) = p2;   // kg=2
      *(u32x4*)(wbp + 768) = p3;   // kg=3
    }
    __syncthreads();   // B2: htile ready (B3 of prev step guarantees old reads done)

    // ---- h A-frags from frag-major tile + 16 h-MFMAs ----
#pragma unroll
    for (int kq = 0; kq < 4; ++kq) {
      f16x8 h0f = *(const f16x8*)(htile + (kq*4+0)*1024 + kg*256 + ((il*16) ^ (((kq*4+0)&7)<<4)));
      f16x8 h1f = *(const f16x8*)(htile + (kq*4+1)*1024 + kg*256 + ((il*16) ^ (((kq*4+1)&7)<<4)));
      f16x8 h2f = *(const f16x8*)(htile + (kq*4+2)*1024 + kg*256 + ((il*16) ^ (((kq*4+2)&7)<<4)));
      f16x8 h3f = *(const f16x8*)(htile + (kq*4+3)*1024 + kg*256 + ((il*16) ^ (((kq*4+3)&7)<<4)));
      ac0 = MFMA(h0f, wreg[16+kq*4+0], ac0);
      ac1 = MFMA(h1f, wreg[16+kq*4+1], ac1);
      ac2 = MFMA(h2f, wreg[16+kq*4+2], ac2);
      ac3 = MFMA(h3f, wreg[16+kq*4+3], ac3);
    }

    // D-frag: col = lane&15, row = (lane>>4)*4 + r  (m89-verified)
#pragma unroll
    for (int r = 0; r < 4; ++r)
      glds[kg*4+r][wv*16+il] = ac0[r] + ac1[r] + ac2[r] + ac3[r];
    __syncthreads();   // B3: glds ready

    // ---- LSTM cell (gate order i,f,g,o) ----
    float gi = glds[bl_e][ 0 + i_e] + bi_;
    float gf = glds[bl_e][16 + i_e] + bf_;
    float gg = glds[bl_e][32 + i_e] + bg_;
    float go = glds[bl_e][48 + i_e] + bo_;
    float si = fsig(gi), sf = fsig(gf), so = fsig(go);
    float tg = ftanh_(gg);
    cst = sf * cst + si * tg;
    float hv = so * ftanh_(cst);

    // ---- publish h(t): one tagged sc0 dword store (tag t+2, parity t&1) ----
    {
      unsigned int hb = __half_as_ushort(__float2half(hv));
      unsigned int pw = ((unsigned int)(t + 2) << 16) | hb;
      unsigned int* hp2 = gbase + (t & 1) * 8192 + bl_e * 512 + col_e;
      asm volatile("global_store_dword %0, %1, off sc0" :: "v"(hp2), "v"(pw) : "memory");
    }

    // ---- HBM out store AFTER publish (off inter-block critical path) ----
    if (dir == 0) {
      out[((size_t)b_e * TT + t) * (2 * HH) + col_e] = hv;
    } else {
      int td = len_e - 1 - t; if (td < 0) td += TT;
      out[((size_t)b_e * TT + td) * (2 * HH) + HH + col_e] = hv;
    }
  }
#undef TCHK
#undef PK
}

extern "C" void kernel_launch(void* const* d_in, const int* in_sizes, int n_in,
                              void* d_out, int out_size, void* d_ws, size_t ws_size,
                              hipStream_t stream) {
  const float* x    = (const float*)d_in[0];
  const float* mask = (const float*)d_in[1];
  const float* h0   = (const float*)d_in[2];
  const float* c0   = (const float*)d_in[3];
  const float* Wi_f = (const float*)d_in[4];
  const float* Wh_f = (const float*)d_in[5];
  const float* b_f  = (const float*)d_in[6];
  const float* Wi_b = (const float*)d_in[7];
  const float* Wh_b = (const float*)d_in[8];
  const float* b_b  = (const float*)d_in[9];
  float* out = (float*)d_out;

  char* ws = (char*)d_ws;
  int*          claim = (int*)(ws + WS_CLAIM);
  int*          lens  = (int*)(ws + WS_LENS);
  unsigned int* hbuf  = (unsigned int*)(ws + WS_HBUF);

  // re-zero ONLY the role counters each call (hbuf is replay-safe by tag design)
  hipMemsetAsync(ws, 0, 256, stream);

  hipLaunchKernelGGL(len_kernel, dim3(1), dim3(64), 0, stream, mask, lens);

  hipFuncSetAttribute((const void*)bilstm_kernel,
                      hipFuncAttributeMaxDynamicSharedMemorySize, LDS_TOTAL);

  // 88KB LDS -> 1 block/CU; grid 256 = CU count -> all co-resident, 32/XCD.
  hipLaunchKernelGGL(bilstm_kernel, dim3(256), dim3(256), LDS_TOTAL, stream,
                     x, lens, h0, c0, Wi_f, Wh_f, b_f, Wi_b, Wh_b, b_b,
                     out, hbuf, claim);
}

// Round 12
// 2782.480 us; speedup vs baseline: 1.8549x; 1.1261x over previous
//
#include <hip/hip_runtime.h>
#include <hip/hip_fp16.h>

typedef _Float16 f16x8 __attribute__((ext_vector_type(8)));
typedef float f32x4 __attribute__((ext_vector_type(4)));

#define TT 512
#define HH 512
#define BB 64

// ws layout (bytes)
#define WS_LENS  4096          // int[64]
#define WS_HBUF  8192          // u64 tagged-h [dir][parity][64][256] = 512 KB
#define WS_ZERO  532480        // memset lens+hbuf each call (determinism)
#define WS_XH    (1u << 20)    // f16 x [64][512][512] = 32 MB
#define WS_GX    36700160u     // f16 gx [2][64*512][2048] = 268 MB (35 MB offset)
#define WS_NEED  305135616ull  // WS_GX + 268435456

// dynamic LDS (bytes) for scan kernel
#define LDS_HT    0            // h tile [16 rows][512 f16], XOR-swizzled = 16 KB
#define LDS_GLDS  16384        // float [16][68] gates bounce
#define LDS_TOTAL 90112        // padded >80KB to hard-force 1 block/CU

#define MFMA(a,b,c) __builtin_amdgcn_mfma_f32_16x16x32_f16((a),(b),(c),0,0,0)

__device__ __forceinline__ float fsig(float x) {
  float ax = __builtin_fabsf(x);
  float t  = __builtin_amdgcn_exp2f(-1.442695041f * ax);
  float r  = __builtin_amdgcn_rcpf(1.0f + t);
  return x >= 0.0f ? r : t * r;
}
__device__ __forceinline__ float ftanh_(float x) {
  float ax = __builtin_fabsf(x);
  float t  = __builtin_amdgcn_exp2f(-2.885390082f * ax);
  float r  = (1.0f - t) * __builtin_amdgcn_rcpf(1.0f + t);
  return x >= 0.0f ? r : -r;
}
__device__ __forceinline__ f16x8 cvt8(const float* p) {
  float4 a = *(const float4*)p, b = *(const float4*)(p + 4);
  f16x8 w;
  w[0]=(_Float16)a.x; w[1]=(_Float16)a.y; w[2]=(_Float16)a.z; w[3]=(_Float16)a.w;
  w[4]=(_Float16)b.x; w[5]=(_Float16)b.y; w[6]=(_Float16)b.z; w[7]=(_Float16)b.w;
  return w;
}

__global__ void len_kernel(const float* __restrict__ mask, int* __restrict__ lens) {
  int b = threadIdx.x;
  if (b < BB) {
    float s = 0.f;
    for (int t = 0; t < TT; ++t) s += mask[b * TT + t];
    lens[b] = (int)(s + 0.5f);
  }
}

__global__ void cvt_x_kernel(const float* __restrict__ x, __half* __restrict__ xh, int n4) {
  int i = blockIdx.x * blockDim.x + threadIdx.x;
  int stride = gridDim.x * blockDim.x;
  for (; i < n4; i += stride) {
    float4 v = ((const float4*)x)[i];
    ushort4 o;
    o.x = __half_as_ushort(__float2half(v.x));
    o.y = __half_as_ushort(__float2half(v.y));
    o.z = __half_as_ushort(__float2half(v.z));
    o.w = __half_as_ushort(__float2half(v.w));
    ((ushort4*)xh)[i] = o;
  }
}

// Input-projection GEMM: gx[dir][row=b*512+t][2048] = xh[row] . Wi_dir^T
// (f16 A from xh; B converted f32->f16 in-register; fp32 accum).
__global__ void gx_kernel(const __half* __restrict__ xh, const float* __restrict__ Wi_f,
                          const float* __restrict__ Wi_b, __half* __restrict__ gx) {
  const int rt = blockIdx.x, ct = blockIdx.y, dir = blockIdx.z;
  const int tid = threadIdx.x, wv = tid >> 6, ln = tid & 63, il = ln & 15, kg = ln >> 4;
  const float* wsrc = dir ? Wi_b : Wi_f;

  const int arow = rt * 128 + wv * 32 + il;
  const __half* ap0 = xh + (size_t)arow * 512 + kg * 8;
  const __half* ap1 = ap0 + 16 * 512;
  const float* bp0 = wsrc + (size_t)(ct * 64 +  0 + il) * 512 + kg * 8;
  const float* bp1 = wsrc + (size_t)(ct * 64 + 16 + il) * 512 + kg * 8;
  const float* bp2 = wsrc + (size_t)(ct * 64 + 32 + il) * 512 + kg * 8;
  const float* bp3 = wsrc + (size_t)(ct * 64 + 48 + il) * 512 + kg * 8;

  f32x4 acc[2][4];
#pragma unroll
  for (int m = 0; m < 2; ++m)
#pragma unroll
    for (int n = 0; n < 4; ++n) acc[m][n] = (f32x4){0.f,0.f,0.f,0.f};

#pragma unroll 4
  for (int ks = 0; ks < 16; ++ks) {
    f16x8 a0 = *(const f16x8*)(ap0 + ks * 32);
    f16x8 a1 = *(const f16x8*)(ap1 + ks * 32);
    f16x8 b0 = cvt8(bp0 + ks * 32);
    f16x8 b1 = cvt8(bp1 + ks * 32);
    f16x8 b2 = cvt8(bp2 + ks * 32);
    f16x8 b3 = cvt8(bp3 + ks * 32);
    acc[0][0] = MFMA(a0, b0, acc[0][0]);
    acc[0][1] = MFMA(a0, b1, acc[0][1]);
    acc[0][2] = MFMA(a0, b2, acc[0][2]);
    acc[0][3] = MFMA(a0, b3, acc[0][3]);
    acc[1][0] = MFMA(a1, b0, acc[1][0]);
    acc[1][1] = MFMA(a1, b1, acc[1][1]);
    acc[1][2] = MFMA(a1, b2, acc[1][2]);
    acc[1][3] = MFMA(a1, b3, acc[1][3]);
  }

  // D-frag: col = lane&15 (=il), row_local = kg*4 + r  (m89-verified)
#pragma unroll
  for (int m = 0; m < 2; ++m)
#pragma unroll
    for (int n = 0; n < 4; ++n)
#pragma unroll
      for (int r = 0; r < 4; ++r) {
        int row = rt * 128 + wv * 32 + m * 16 + kg * 4 + r;
        int col = ct * 64 + n * 16 + il;
        gx[((size_t)dir * 32768 + row) * 2048 + col] = __float2half(acc[m][n][r]);
      }
}

// Recurrent scan. Static roles (r8-proven): bid = dir*128 + bg*32 + cg.
// h exchange: u64 tag-in-data {tag:32, h_odd:f16, h_even:f16} via AGENT-scope
// atomics (r8-proven: compiler emits real cache-bypass; sc0-asm does NOT
// bypass L1 on gfx950 -- r9 only worked because its x-loads thrashed L1).
// has_gx: input projection precomputed -> loop has NO x loads / x MFMAs.
// Spin bailout: a genuine sync failure surfaces as fast absmax-fail, not timeout.
__global__ void __launch_bounds__(256, 1)
bilstm_kernel(const float* __restrict__ x, const int* __restrict__ lens,
              const float* __restrict__ h0, const float* __restrict__ c0,
              const float* __restrict__ Wi_f, const float* __restrict__ Wh_f,
              const float* __restrict__ b_f,
              const float* __restrict__ Wi_b, const float* __restrict__ Wh_b,
              const float* __restrict__ b_b,
              float* __restrict__ out, unsigned long long* hbuf,
              const __half* __restrict__ gx, int has_gx)
{
  extern __shared__ __align__(16) char smem[];
  char* htile = smem + LDS_HT;
  float (*glds)[68] = (float (*)[68])(smem + LDS_GLDS);

  const int bid = blockIdx.x;
  const int dir = bid >> 7;
  const int bg  = (bid >> 5) & 3;
  const int cg  = bid & 31;
  const int tid = threadIdx.x;
  const int wv  = tid >> 6, ln = tid & 63, il = ln & 15, kg = ln >> 4;

  const float* Wi = dir ? Wi_b : Wi_f;
  const float* Wh = dir ? Wh_b : Wh_f;
  const float* bv = dir ? b_b  : b_f;

  unsigned long long* hb64 = hbuf + (size_t)dir * (2 * BB * 256);  // [parity][64][256] u64

  // ---- stationary weights -> REGISTERS ----
  const int jrow = wv * HH + cg * 16 + il;
  f16x8 wreg[32];
#pragma unroll
  for (int kk = 0; kk < 32; ++kk) {
    int k0 = kk * 32 + kg * 8;
    const float* src = (k0 < 512) ? (Wi + (size_t)jrow * 512 + k0)
                                  : (Wh + (size_t)jrow * 512 + (k0 - 512));
    wreg[kk] = cvt8(src);
  }

  // ---- elementwise role ----
  const int bl_e = tid >> 4, i_e = tid & 15;
  const int b_e = bg * 16 + bl_e, col_e = cg * 16 + i_e;
  float cst = c0[(size_t)b_e * HH + col_e];
  const float bi_ = bv[0*HH+col_e], bf_ = bv[1*HH+col_e],
              bg_ = bv[2*HH+col_e], bo_ = bv[3*HH+col_e];
  const int len_e = lens[b_e];

  // ---- gemm role (fallback path): A-frag row = batch ----
  const int b_g = bg * 16 + il;
  const int len_b = lens[b_g];

  // ---- init h(-1): parity 1, tag 1, paired u64 (agent scope) ----
  {
    unsigned int hbits = __half_as_ushort(__float2half(h0[(size_t)b_e * HH + col_e]));
    unsigned int pb = __shfl_xor((int)hbits, 1);
    if ((tid & 1) == 0) {
      unsigned long long pw = (1ull << 32) | ((unsigned long long)pb << 16) | hbits;
      __hip_atomic_store(hb64 + (size_t)1 * BB * 256 + (size_t)b_e * 256 + (col_e >> 1), pw,
                         __ATOMIC_RELAXED, __HIP_MEMORY_SCOPE_AGENT);
    }
  }
  __syncthreads();

  for (int t = 0; t < TT; ++t) {
    // pin the live weight fragments in VGPRs (defeats remat; zero instructions)
    if (has_gx) {
      asm volatile("" : "+v"(wreg[16]),"+v"(wreg[17]),"+v"(wreg[18]),"+v"(wreg[19]),
                        "+v"(wreg[20]),"+v"(wreg[21]),"+v"(wreg[22]),"+v"(wreg[23]),
                        "+v"(wreg[24]),"+v"(wreg[25]),"+v"(wreg[26]),"+v"(wreg[27]),
                        "+v"(wreg[28]),"+v"(wreg[29]),"+v"(wreg[30]),"+v"(wreg[31]));
    } else {
      asm volatile("" : "+v"(wreg[0]),"+v"(wreg[1]),"+v"(wreg[2]),"+v"(wreg[3]),
                        "+v"(wreg[4]),"+v"(wreg[5]),"+v"(wreg[6]),"+v"(wreg[7]),
                        "+v"(wreg[8]),"+v"(wreg[9]),"+v"(wreg[10]),"+v"(wreg[11]),
                        "+v"(wreg[12]),"+v"(wreg[13]),"+v"(wreg[14]),"+v"(wreg[15]));
      asm volatile("" : "+v"(wreg[16]),"+v"(wreg[17]),"+v"(wreg[18]),"+v"(wreg[19]),
                        "+v"(wreg[20]),"+v"(wreg[21]),"+v"(wreg[22]),"+v"(wreg[23]),
                        "+v"(wreg[24]),"+v"(wreg[25]),"+v"(wreg[26]),"+v"(wreg[27]),
                        "+v"(wreg[28]),"+v"(wreg[29]),"+v"(wreg[30]),"+v"(wreg[31]));
    }

    // ---- issue h(t-1) tagged u64 loads FIRST (dense: lane i -> unit i) ----
    const unsigned long long* hs = hb64 + (size_t)((t + 1) & 1) * BB * 256 + (size_t)bg * 16 * 256;
    const unsigned int expT = (unsigned int)(t + 1);
    unsigned long long hwv[16];
#pragma unroll
    for (int s = 0; s < 16; ++s)
      hwv[s] = __hip_atomic_load(hs + s * 256 + tid, __ATOMIC_RELAXED, __HIP_MEMORY_SCOPE_AGENT);

    f32x4 ac0 = {0.f,0.f,0.f,0.f}, ac1 = {0.f,0.f,0.f,0.f};
    f32x4 ac2 = {0.f,0.f,0.f,0.f}, ac3 = {0.f,0.f,0.f,0.f};

    // ---- input-projection gates (precomputed) or fallback x phase ----
    float gxa0 = 0.f, gxa1 = 0.f, gxa2 = 0.f, gxa3 = 0.f;
    if (has_gx) {
      int tse;
      if (dir == 0) tse = t;
      else { int v = len_e + (TT - 1) - t; if (v >= TT) v -= TT; tse = v; }
      const __half* gp = gx + ((size_t)dir * 32768 + (size_t)b_e * TT + tse) * 2048 + col_e;
      gxa0 = __half2float(gp[0]);
      gxa1 = __half2float(gp[512]);
      gxa2 = __half2float(gp[1024]);
      gxa3 = __half2float(gp[1536]);
    } else {
      int tsrc;
      if (dir == 0) tsrc = t;
      else { int v = len_b + (TT - 1) - t; if (v >= TT) v -= TT; tsrc = v; }
      const float* xrow = x + ((size_t)b_g * TT + tsrc) * 512;
#pragma unroll
      for (int kq = 0; kq < 4; ++kq) {
        f16x8 w0 = cvt8(xrow + (kq*4+0)*32 + kg*8);
        f16x8 w1 = cvt8(xrow + (kq*4+1)*32 + kg*8);
        f16x8 w2 = cvt8(xrow + (kq*4+2)*32 + kg*8);
        f16x8 w3 = cvt8(xrow + (kq*4+3)*32 + kg*8);
        ac0 = MFMA(w0, wreg[kq*4+0], ac0);
        ac1 = MFMA(w1, wreg[kq*4+1], ac1);
        ac2 = MFMA(w2, wreg[kq*4+2], ac2);
        ac3 = MFMA(w3, wreg[kq*4+3], ac3);
      }
    }

    // ---- tag check; slow path: dense reload-all + sleep; bailout = diagnostic ----
    {
      bool ok = true;
#pragma unroll
      for (int s = 0; s < 16; ++s) ok &= ((unsigned int)(hwv[s] >> 32) == expT);
      unsigned long long tspin = 0;
      while (!__all(ok)) {
        __builtin_amdgcn_s_sleep(1);
#pragma unroll
        for (int s = 0; s < 16; ++s)
          hwv[s] = __hip_atomic_load(hs + s * 256 + tid, __ATOMIC_RELAXED, __HIP_MEMORY_SCOPE_AGENT);
        ok = true;
#pragma unroll
        for (int s = 0; s < 16; ++s) ok &= ((unsigned int)(hwv[s] >> 32) == expT);
        if (tspin == 0) tspin = __builtin_readcyclecounter();
        else if (__builtin_readcyclecounter() - tspin > (1ull << 31)) break;
      }
    }

    // ---- stage h into swizzled LDS tile (strip tags; 4B = 2 f16 per unit) ----
#pragma unroll
    for (int s = 0; s < 16; ++s) {
      unsigned int lo = (unsigned int)hwv[s];           // [h_odd:16 | h_even:16]
      *(unsigned int*)(htile + s * 1024 + ((tid * 4) ^ ((s & 7) << 4))) = lo;
    }
    __syncthreads();   // B2: htile ready

    // ---- h A-frags (one ds_read_b128 per K-slice) + 16 h-MFMAs ----
#pragma unroll
    for (int kk = 0; kk < 16; kk += 4) {
      f16x8 h0f = *(const f16x8*)(htile + il * 1024 + (((kk+0)*64 + kg*16) ^ ((il & 7) << 4)));
      f16x8 h1f = *(const f16x8*)(htile + il * 1024 + (((kk+1)*64 + kg*16) ^ ((il & 7) << 4)));
      f16x8 h2f = *(const f16x8*)(htile + il * 1024 + (((kk+2)*64 + kg*16) ^ ((il & 7) << 4)));
      f16x8 h3f = *(const f16x8*)(htile + il * 1024 + (((kk+3)*64 + kg*16) ^ ((il & 7) << 4)));
      ac0 = MFMA(h0f, wreg[16 + kk + 0], ac0);
      ac1 = MFMA(h1f, wreg[16 + kk + 1], ac1);
      ac2 = MFMA(h2f, wreg[16 + kk + 2], ac2);
      ac3 = MFMA(h3f, wreg[16 + kk + 3], ac3);
    }

    // D-frag: col = lane&15, row = (lane>>4)*4 + r  (m89-verified)
#pragma unroll
    for (int r = 0; r < 4; ++r)
      glds[kg*4+r][wv*16+il] = ac0[r] + ac1[r] + ac2[r] + ac3[r];
    __syncthreads();   // B3: glds ready

    // ---- LSTM cell (gate order i,f,g,o) ----
    float gi = glds[bl_e][ 0 + i_e] + gxa0 + bi_;
    float gf = glds[bl_e][16 + i_e] + gxa1 + bf_;
    float gg = glds[bl_e][32 + i_e] + gxa2 + bg_;
    float go = glds[bl_e][48 + i_e] + gxa3 + bo_;
    float si = fsig(gi), sf = fsig(gf), so = fsig(go);
    float tg = ftanh_(gg);
    cst = sf * cst + si * tg;
    float hv = so * ftanh_(cst);

    // ---- publish h(t): paired u64 tagged store (tag t+2), parity t&1 ----
    {
      unsigned int hbits = __half_as_ushort(__float2half(hv));
      unsigned int pb = __shfl_xor((int)hbits, 1);
      if ((tid & 1) == 0) {
        unsigned long long pw = ((unsigned long long)(unsigned int)(t + 2) << 32)
                              | ((unsigned long long)pb << 16) | hbits;
        __hip_atomic_store(hb64 + (size_t)(t & 1) * BB * 256 + (size_t)b_e * 256 + (col_e >> 1), pw,
                           __ATOMIC_RELAXED, __HIP_MEMORY_SCOPE_AGENT);
      }
    }

    // ---- HBM out store AFTER publish (off inter-block critical path) ----
    if (dir == 0) {
      out[((size_t)b_e * TT + t) * (2 * HH) + col_e] = hv;
    } else {
      int td = len_e - 1 - t; if (td < 0) td += TT;
      out[((size_t)b_e * TT + td) * (2 * HH) + HH + col_e] = hv;
    }
  }
}

extern "C" void kernel_launch(void* const* d_in, const int* in_sizes, int n_in,
                              void* d_out, int out_size, void* d_ws, size_t ws_size,
                              hipStream_t stream) {
  const float* x    = (const float*)d_in[0];
  const float* mask = (const float*)d_in[1];
  const float* h0   = (const float*)d_in[2];
  const float* c0   = (const float*)d_in[3];
  const float* Wi_f = (const float*)d_in[4];
  const float* Wh_f = (const float*)d_in[5];
  const float* b_f  = (const float*)d_in[6];
  const float* Wi_b = (const float*)d_in[7];
  const float* Wh_b = (const float*)d_in[8];
  const float* b_b  = (const float*)d_in[9];
  float* out = (float*)d_out;

  char* ws = (char*)d_ws;
  int*                lens = (int*)(ws + WS_LENS);
  unsigned long long* hbuf = (unsigned long long*)(ws + WS_HBUF);
  __half*             xh   = (__half*)(ws + WS_XH);
  __half*             gxb  = (__half*)(ws + WS_GX);

  const int has_gx = (ws_size >= WS_NEED) ? 1 : 0;

  // zero lens + tagged-h region every call (tags restart at 1; 0 never matches)
  hipMemsetAsync(ws, 0, WS_ZERO, stream);

  hipLaunchKernelGGL(len_kernel, dim3(1), dim3(64), 0, stream, mask, lens);

  if (has_gx) {
    hipLaunchKernelGGL(cvt_x_kernel, dim3(2048), dim3(256), 0, stream,
                       x, xh, (BB * TT * 512) / 4);
    // input projection for both dirs: [2][32768 rows][2048 cols], K=512
    hipLaunchKernelGGL(gx_kernel, dim3(256, 32, 2), dim3(256), 0, stream,
                       xh, Wi_f, Wi_b, gxb);
  }

  hipFuncSetAttribute((const void*)bilstm_kernel,
                      hipFuncAttributeMaxDynamicSharedMemorySize, LDS_TOTAL);

  // 88KB LDS -> 1 block/CU; grid 256 = CU count -> all co-resident.
  hipLaunchKernelGGL(bilstm_kernel, dim3(256), dim3(256), LDS_TOTAL, stream,
                     x, lens, h0, c0, Wi_f, Wh_f, b_f, Wi_b, Wh_b, b_b,
                     out, hbuf, gxb, has_gx);
}